// Round 11
// baseline (4385.239 us; speedup 1.0000x reference)
//
#include <hip/hip_runtime.h>
#include <stdint.h>
#include <stddef.h>

typedef unsigned short bf16;
typedef __attribute__((ext_vector_type(8))) short short8;   // 8 bf16 (MFMA A/B frag)
typedef __attribute__((ext_vector_type(4))) float f32x4;    // MFMA C/D frag

__device__ __forceinline__ float bf2f(unsigned short u){
  union { uint32_t i; float f; } x; x.i = ((uint32_t)u) << 16; return x.f;
}
__device__ __forceinline__ unsigned short f2bf(float f){
  union { float f; uint32_t i; } x; x.f = f;
  uint32_t r = x.i + 0x7FFFu + ((x.i >> 16) & 1u);  // RNE
  return (unsigned short)(r >> 16);
}
__device__ __forceinline__ uint32_t pk2(float a, float b){
  return (uint32_t)f2bf(a) | ((uint32_t)f2bf(b) << 16);
}

// ---- fp8 e4m3fn (OCP) encode/decode -- internal compression only ----
__device__ __forceinline__ uint8_t f2fp8_sw(float f){
  uint32_t b = __float_as_uint(f);
  uint32_t s = (b >> 24) & 0x80u;
  uint32_t x = b & 0x7fffffffu;
  if (x >= 0x43e00000u) return (uint8_t)(s | 0x7eu);        // clamp to ±448
  if (x < 0x3c800000u){                                     // subnormal
    uint32_t q = (uint32_t)rintf(__uint_as_float(x) * 512.f);
    return (uint8_t)(s | q);
  }
  uint32_t lsb = (x >> 20) & 1u;
  x += 0x7ffffu + lsb;                                      // RNE at bit 20
  uint32_t u = (((x >> 23) - 120u) << 3) | ((x >> 20) & 7u);
  if (u > 0x7eu) u = 0x7eu;
  return (uint8_t)(s | u);
}
__device__ __forceinline__ float fp8_dec1_sw(uint32_t u){
  uint32_t e = (u >> 3) & 15u, m = u & 7u;
  float v = e ? __uint_as_float(((e + 120u) << 23) | (m << 20))
              : (float)m * 0.001953125f;
  return (u & 0x80u) ? -v : v;
}

#if __has_builtin(__builtin_amdgcn_cvt_pk_f32_fp8) && __has_builtin(__builtin_amdgcn_cvt_pk_fp8_f32)
#define FP8_HW 1
#else
#define FP8_HW 0
#endif

// single-byte decode: 1 VALU op (no LDS LUT -> no bank conflicts)
__device__ __forceinline__ float fp8_dec1(uint32_t b){
#if FP8_HW
  auto lo = __builtin_amdgcn_cvt_pk_f32_fp8((int)b, false);
  return lo[0];
#else
  return fp8_dec1_sw(b);
#endif
}
__device__ __forceinline__ void fp8_dec4(uint32_t w, float* o){
#if FP8_HW
  auto lo = __builtin_amdgcn_cvt_pk_f32_fp8((int)w, false);
  auto hi = __builtin_amdgcn_cvt_pk_f32_fp8((int)w, true);
  o[0] = lo[0]; o[1] = lo[1]; o[2] = hi[0]; o[3] = hi[1];
#else
  o[0] = fp8_dec1_sw(w & 0xffu);        o[1] = fp8_dec1_sw((w >> 8) & 0xffu);
  o[2] = fp8_dec1_sw((w >> 16) & 0xffu); o[3] = fp8_dec1_sw(w >> 24);
#endif
}
__device__ __forceinline__ uint8_t fp8_enc1(float v){
#if FP8_HW
  return (uint8_t)(__builtin_amdgcn_cvt_pk_fp8_f32(v, v, 0, false) & 0xff);
#else
  return f2fp8_sw(v);
#endif
}
__device__ __forceinline__ uint32_t fp8_enc4(float a, float b, float c, float d){
#if FP8_HW
  int w = 0;
  w = __builtin_amdgcn_cvt_pk_fp8_f32(a, b, w, false);
  w = __builtin_amdgcn_cvt_pk_fp8_f32(c, d, w, true);
  return (uint32_t)w;
#else
  return (uint32_t)f2fp8_sw(a) | ((uint32_t)f2fp8_sw(b) << 8)
       | ((uint32_t)f2fp8_sw(c) << 16) | ((uint32_t)f2fp8_sw(d) << 24);
#endif
}

// ---------------- threefry2x32 (matches harness jax; verified R2-R10) ----------------
__host__ __device__ __forceinline__ uint32_t rotl32_(uint32_t x, int d){
  return (x << d) | (x >> (32 - d));
}
__host__ __device__ inline void tf2x32(uint32_t k0, uint32_t k1, uint32_t x0, uint32_t x1,
                                       uint32_t* o0, uint32_t* o1){
  uint32_t k2 = k0 ^ k1 ^ 0x1BD11BDAu;
#define TF_R4(ra,rb,rc,rd) \
  x0 += x1; x1 = rotl32_(x1,ra); x1 ^= x0; \
  x0 += x1; x1 = rotl32_(x1,rb); x1 ^= x0; \
  x0 += x1; x1 = rotl32_(x1,rc); x1 ^= x0; \
  x0 += x1; x1 = rotl32_(x1,rd); x1 ^= x0;
  x0 += k0; x1 += k1;
  TF_R4(13,15,26,6)  x0 += k1; x1 += k2 + 1u;
  TF_R4(17,29,16,24) x0 += k2; x1 += k0 + 2u;
  TF_R4(13,15,26,6)  x0 += k0; x1 += k1 + 3u;
  TF_R4(17,29,16,24) x0 += k1; x1 += k2 + 4u;
  TF_R4(13,15,26,6)  x0 += k2; x1 += k0 + 5u;
  *o0 = x0; *o1 = x1;
#undef TF_R4
}

// ---------------- small utils ----------------
__global__ void k_zeroi(int* __restrict__ p, int n){
  int i = blockIdx.x * 256 + threadIdx.x;
  if (i < n) p[i] = 0;
}
__global__ void k_f2bf(const float* __restrict__ in, bf16* __restrict__ out, int n4){
  int i = blockIdx.x * 256 + threadIdx.x;
  if (i < n4){
    float4 v = ((const float4*)in)[i];
    ushort4 u; u.x = f2bf(v.x); u.y = f2bf(v.y); u.z = f2bf(v.z); u.w = f2bf(v.w);
    ((ushort4*)out)[i] = u;
  }
}
__global__ void k_f2fp8(const float* __restrict__ in, uint8_t* __restrict__ out, int n4){
  int i = blockIdx.x * 256 + threadIdx.x;
  if (i < n4){
    float4 v = ((const float4*)in)[i];
    ((uint32_t*)out)[i] = fp8_enc4(v.x, v.y, v.z, v.w);
  }
}

// ---------------- CSR build ----------------
__global__ void k_deg(const int* __restrict__ dst, int* __restrict__ deg, int E){
  int i = blockIdx.x * 256 + threadIdx.x;
  if (i < E) atomicAdd(&deg[dst[i]], 1);
}
__global__ __launch_bounds__(256)
void k_scan_partial(const int* __restrict__ in, int* __restrict__ exc,
                    int* __restrict__ bsum, int n){
  __shared__ int tmp[256];
  int t = threadIdx.x, i = blockIdx.x * 256 + t;
  int v = (i < n) ? in[i] : 0;
  tmp[t] = v; __syncthreads();
  #pragma unroll
  for (int off = 1; off < 256; off <<= 1){
    int u = (t >= off) ? tmp[t - off] : 0; __syncthreads();
    tmp[t] += u; __syncthreads();
  }
  if (i < n) exc[i] = tmp[t] - v;
  if (t == 255) bsum[blockIdx.x] = tmp[255];
}
__global__ __launch_bounds__(1024)
void k_scan_bsum(int* __restrict__ bsum, int nb, int* __restrict__ total_out){
  __shared__ int tmp[1024];
  int t = threadIdx.x;
  int v = (t < nb) ? bsum[t] : 0;
  tmp[t] = v; __syncthreads();
  #pragma unroll
  for (int off = 1; off < 1024; off <<= 1){
    int u = (t >= off) ? tmp[t - off] : 0; __syncthreads();
    tmp[t] += u; __syncthreads();
  }
  if (t < nb) bsum[t] = tmp[t] - v;
  if (t == 1023) *total_out = tmp[1023];
}
__global__ void k_scan_add(int* __restrict__ exc, const int* __restrict__ bsum, int n){
  int i = blockIdx.x * 256 + threadIdx.x;
  if (i < n) exc[i] += bsum[blockIdx.x];
}
__global__ void k_fill(const int* __restrict__ src, const int* __restrict__ dst,
                       const int* __restrict__ rs, int* __restrict__ cur,
                       int* __restrict__ cs, int E){
  int i = blockIdx.x * 256 + threadIdx.x;
  if (i < E){
    int d = dst[i];
    int p = atomicAdd(&cur[d], 1);
    cs[rs[d] + p] = src[i];
  }
}

// ---------------- layer-1 mean aggregation from fp8 x (128B rows) ----------------
// 4 nodes per 256-thread block (1 wave/node); per-wave LDS cs segment.
#define AGG_CHUNK 128
__global__ __launch_bounds__(256)
void k_agg128_8(const uint8_t* __restrict__ X8, const int* __restrict__ rs,
                const int* __restrict__ cs, bf16* __restrict__ out, int nNodes){
  __shared__ int ics4[4][AGG_CHUNK];
  const int wv = threadIdx.x >> 6, lane = threadIdx.x & 63;
  const int node = blockIdx.x * 4 + wv;
  if (node >= nNodes) return;
  int* ics = ics4[wv];
  const int hl = lane >> 5, cl = lane & 31;
  const int s0 = rs[node], s1 = rs[node + 1];
  float a[4] = {0.f, 0.f, 0.f, 0.f};
  for (int cb = s0; cb < s1; cb += AGG_CHUNK){
    const int cnt = (s1 - cb < AGG_CHUNK) ? (s1 - cb) : AGG_CHUNK;
    __builtin_amdgcn_wave_barrier();
    for (int i = lane; i < cnt; i += 64) ics[i] = cs[cb + i];
    __builtin_amdgcn_wave_barrier();
    int e = 0;
    for (; e + 16 <= cnt; e += 16){
      uint32_t w[8];
      #pragma unroll
      for (int j = 0; j < 8; ++j){
        int idx = ics[e + j * 2 + hl];
        w[j] = *(const uint32_t*)(X8 + (size_t)idx * 128 + (cl << 2));
      }
      #pragma unroll
      for (int j = 0; j < 8; ++j){
        float d[4];
        fp8_dec4(w[j], d);
        a[0] += d[0]; a[1] += d[1]; a[2] += d[2]; a[3] += d[3];
      }
    }
    for (; e + 2 <= cnt; e += 2){
      int idx = ics[e + hl];
      uint32_t w = *(const uint32_t*)(X8 + (size_t)idx * 128 + (cl << 2));
      float d[4];
      fp8_dec4(w, d);
      a[0] += d[0]; a[1] += d[1]; a[2] += d[2]; a[3] += d[3];
    }
    if (e < cnt && hl == 0){   // single leftover edge: low half only
      int idx = ics[e];
      uint32_t w = *(const uint32_t*)(X8 + (size_t)idx * 128 + (cl << 2));
      float d[4];
      fp8_dec4(w, d);
      a[0] += d[0]; a[1] += d[1]; a[2] += d[2]; a[3] += d[3];
    }
  }
  #pragma unroll
  for (int j = 0; j < 4; ++j) a[j] += __shfl_xor(a[j], 32);
  if (lane < 32){
    float inv = 1.f / fmaxf((float)(s1 - s0), 1.f);
    ushort4 u;
    u.x = f2bf(a[0] * inv); u.y = f2bf(a[1] * inv);
    u.z = f2bf(a[2] * inv); u.w = f2bf(a[3] * inv);
    *(ushort4*)(out + (size_t)node * 128 + (cl << 2)) = u;
  }
}

// ---------------- fused per-g weight prep ----------------
__global__ void k_prep(const float* __restrict__ Wl1g, const float* __restrict__ Wr1g,
                       const float* __restrict__ b1g,
                       const float* __restrict__ Wl2g, const float* __restrict__ Wr2g,
                       const float* __restrict__ b2g, int O,
                       bf16* __restrict__ Bt_ha, bf16* __restrict__ Bt_ht,
                       bf16* __restrict__ BT2a, bf16* __restrict__ BT2t,
                       float* __restrict__ bc1, float* __restrict__ bc2){
  int i = blockIdx.x * 256 + threadIdx.x;
  const int R0 = 256 * 384, R1 = 256 * 256;
  const int R2 = 3 * O * 256, R3 = 2 * O * 256;
  if (i < R0){
    int n = i / 384, k = i - n * 384;
    int seg = k >> 7, kk = k & 127;
    float v;
    if (seg == 0)      v = Wl1g[(size_t)(128 + kk) * 256 + n];
    else if (seg == 1) v = Wl1g[(size_t)(256 + kk) * 256 + n];
    else               v = Wr1g[(size_t)(128 + kk) * 256 + n] + Wr1g[(size_t)(256 + kk) * 256 + n];
    Bt_ha[(size_t)n * 384 + k] = f2bf(v);
    return;
  }
  i -= R0;
  if (i < R1){
    int n = i >> 8, k = i & 255;
    int kk = k & 127;
    float v = (k < 128) ? Wl1g[(size_t)kk * 256 + n] : Wr1g[(size_t)kk * 256 + n];
    Bt_ht[(size_t)n * 256 + k] = f2bf(v);
    return;
  }
  i -= R1;
  if (i < R2){
    int n = i >> 8, k = i & 255;
    int strip = n / O, r = n - strip * O;
    float v;
    if (strip == 0)      v = Wl2g[(size_t)k * O + r];
    else if (strip == 1) v = Wl2g[(size_t)512 * O + (size_t)k * O + r];
    else                 v = Wr2g[(size_t)256 * O + (size_t)k * O + r]
                           + Wr2g[(size_t)512 * O + (size_t)k * O + r];
    BT2a[(size_t)n * 256 + k] = f2bf(v);
    return;
  }
  i -= R2;
  if (i < R3){
    int n = i >> 8, k = i & 255;
    int strip = n / O, r = n - strip * O;
    float v = (strip == 0) ? Wl2g[(size_t)256 * O + (size_t)k * O + r]
                           : Wr2g[(size_t)k * O + r];
    BT2t[(size_t)n * 256 + k] = f2bf(v);
    return;
  }
  i -= R3;
  if (i < 256){ bc1[i] = b1g[256 + i] + b1g[512 + i]; return; }
  i -= 256;
  if (i < O) bc2[i] = b2g[O + i] + b2g[2 * O + i];
}

// ---------------- MFMA GEMM, 128x256 tile (4 waves 2x2, per-wave 64x128, acc[4][8]) ----------------
// A-panel read ONCE per 256 output cols (layer1: single pass).
template<int EPI>
__global__ __launch_bounds__(256)
void k_gemm_mfma(const bf16* __restrict__ A0, const bf16* __restrict__ A1,
                 const bf16* __restrict__ A2, int lda,
                 const bf16* __restrict__ Bt, int ldb,
                 int M, int N, int Ktot,
                 bf16* __restrict__ hC,
                 uint8_t* __restrict__ z0, uint8_t* __restrict__ z1,
                 float* __restrict__ outF, const float* __restrict__ bias,
                 int O, int zoff, uint32_t dk0, uint32_t dk1){
  __shared__ bf16 As[128][40];   // 80B row stride: 16B-aligned, mild bank aliasing
  __shared__ bf16 Bs[256][40];
  const int tid = threadIdx.x;
  const int w = tid >> 6, l = tid & 63;
  const int wr = w >> 1, wc = w & 1;
  const int r0 = blockIdx.y * 128, c0 = blockIdx.x * 256;

  f32x4 acc[4][8] = {};

  const int sm = tid >> 1, sk = (tid & 1) * 16;   // A staging: 2 thr/row
  const int arow = r0 + sm;
  const int brow = c0 + tid;                       // B staging: 1 thr/row (64B)
  const int lr = l & 15, g8 = (l >> 4) * 8;

  for (int kk = 0; kk < Ktot; kk += 32){
    const int seg = kk >> 7, koff = (kk & 127) + sk;
    const bf16* Ap = (seg == 0) ? A0 : ((seg == 1) ? A1 : A2);
    uint4 wa0 = {0,0,0,0}, wa1 = {0,0,0,0};
    if (arow < M){
      const uint4* p = (const uint4*)(Ap + (size_t)arow * lda + koff);
      wa0 = p[0]; wa1 = p[1];
    }
    uint4 wb0 = {0,0,0,0}, wb1 = {0,0,0,0}, wb2 = {0,0,0,0}, wb3 = {0,0,0,0};
    if (brow < N){
      const uint4* p = (const uint4*)(Bt + (size_t)brow * ldb + kk);
      wb0 = p[0]; wb1 = p[1]; wb2 = p[2]; wb3 = p[3];
    }
    __syncthreads();
    *(uint4*)&As[sm][sk]      = wa0;
    *(uint4*)&As[sm][sk + 8]  = wa1;
    *(uint4*)&Bs[tid][0]      = wb0;
    *(uint4*)&Bs[tid][8]      = wb1;
    *(uint4*)&Bs[tid][16]     = wb2;
    *(uint4*)&Bs[tid][24]     = wb3;
    __syncthreads();
    short8 af[4];
    #pragma unroll
    for (int f = 0; f < 4; ++f)
      af[f] = *(const short8*)&As[wr * 64 + f * 16 + lr][g8];
    #pragma unroll
    for (int j = 0; j < 8; ++j){
      short8 bj = *(const short8*)&Bs[wc * 128 + j * 16 + lr][g8];
      #pragma unroll
      for (int i = 0; i < 4; ++i)
        acc[i][j] = __builtin_amdgcn_mfma_f32_16x16x32_bf16(af[i], bj, acc[i][j], 0, 0, 0);
    }
  }
  // C/D map: col=lane&15, row=(lane>>4)*4+reg
  #pragma unroll
  for (int rt = 0; rt < 4; ++rt){
    #pragma unroll
    for (int ct = 0; ct < 8; ++ct){
      #pragma unroll
      for (int r = 0; r < 4; ++r){
        int row = r0 + wr * 64 + rt * 16 + (l >> 4) * 4 + r;
        int col = c0 + wc * 128 + ct * 16 + lr;
        if (row < M && col < N){
          float v = acc[rt][ct][r];
          if (EPI == 0){
            v += bias[col];
            uint32_t o0, o1;
            tf2x32(dk0, dk1, 0u, (uint32_t)(row * 256 + col), &o0, &o1);
            float a = fmaxf(v, 0.f) * 2.f;
            hC[(size_t)row * 256 + col] = ((o0 ^ o1) >> 31) ? (bf16)0 : f2bf(a);
          } else {
            int s = (col >= O) + (EPI == 1 ? (col >= 2 * O) : 0);
            int lc = col - s * O;
            const int fs = (EPI == 1) ? 2 : 1;
            if (s == fs){
              outF[(size_t)row * O + lc] = v + bias[lc];
            } else {
              uint8_t* d = (s == 0) ? z0 : z1;
              d[(size_t)row * 192 + zoff + lc] = fp8_enc1(v);
            }
          }
        }
      }
    }
  }
}

// ---------------- fused assembles: LDS-staged cs + byte gather + VALU fp8 decode ----------
#define ASM_CHUNK 256
__global__ __launch_bounds__(192)
void k_assemble_t(const uint8_t* __restrict__ z, const int* __restrict__ rs,
                  const int* __restrict__ cs,
                  float* __restrict__ o0, float* __restrict__ o1, float* __restrict__ o2){
  __shared__ int ics[ASM_CHUNK];
  __shared__ float sb[179];
  __shared__ float lse[3];
  const int node = blockIdx.x, t = threadIdx.x;
  const bool act = t < 179;
  const int h = (t < 129) ? 0 : ((t < 161) ? 1 : 2);
  const int base = (h == 0) ? 0 : ((h == 1) ? 129 : 161);
  const int Oh = (h == 0) ? 129 : ((h == 1) ? 32 : 18);
  const int s0 = rs[node], s1 = rs[node + 1];
  float acc = 0.f;
  for (int cb = s0; cb < s1; cb += ASM_CHUNK){
    const int cnt = (s1 - cb < ASM_CHUNK) ? (s1 - cb) : ASM_CHUNK;
    __syncthreads();
    for (int i = t; i < cnt; i += 192) ics[i] = cs[cb + i];
    __syncthreads();
    int e = 0;
    for (; e + 8 <= cnt; e += 8){
      if (act){
        uint32_t b[8];
        #pragma unroll
        for (int j = 0; j < 8; ++j) b[j] = z[(size_t)ics[e + j] * 192 + t];
        #pragma unroll
        for (int j = 0; j < 8; ++j) acc += fp8_dec1(b[j]);
      }
    }
    for (; e < cnt; ++e)
      if (act) acc += fp8_dec1((uint32_t)z[(size_t)ics[e] * 192 + t]);
  }
  const float inv = 1.f / fmaxf((float)(s1 - s0), 1.f);
  float* orow = ((h == 0) ? o0 : ((h == 1) ? o1 : o2)) + (size_t)node * Oh + (t - base);
  float v = 0.f;
  if (act) v = *orow + acc * inv;
  __syncthreads();
  if (act) sb[t] = v;
  __syncthreads();
  const int wv = t >> 6, ln = t & 63;
  {
    const int b = (wv == 0) ? 0 : ((wv == 1) ? 129 : 161);
    const int W = (wv == 0) ? 129 : ((wv == 1) ? 32 : 18);
    float m = -3.4e38f;
    for (int i = ln; i < W; i += 64) m = fmaxf(m, sb[b + i]);
    #pragma unroll
    for (int o = 32; o; o >>= 1) m = fmaxf(m, __shfl_xor(m, o));
    float s = 0.f;
    for (int i = ln; i < W; i += 64) s += expf(sb[b + i] - m);
    #pragma unroll
    for (int o = 32; o; o >>= 1) s += __shfl_xor(s, o);
    if (ln == 0) lse[wv] = m + logf(s);
  }
  __syncthreads();
  if (act) *orow = v - lse[h];
}

__global__ __launch_bounds__(192)
void k_assemble_a(const uint8_t* __restrict__ zT, const uint8_t* __restrict__ zA,
                  const int* __restrict__ rs_ta, const int* __restrict__ cs_ta,
                  const int* __restrict__ rs_aa, const int* __restrict__ cs_aa,
                  float* __restrict__ o0, float* __restrict__ o1, float* __restrict__ o2){
  __shared__ int ics[ASM_CHUNK];
  __shared__ float sb[179];
  __shared__ float lse[3];
  const int node = blockIdx.x, t = threadIdx.x;
  const bool act = t < 179;
  const int h = (t < 129) ? 0 : ((t < 161) ? 1 : 2);
  const int base = (h == 0) ? 0 : ((h == 1) ? 129 : 161);
  const int Oh = (h == 0) ? 129 : ((h == 1) ? 32 : 18);
  float accT = 0.f, accA = 0.f;
  int s0 = rs_ta[node], s1 = rs_ta[node + 1];
  const float invT = 1.f / fmaxf((float)(s1 - s0), 1.f);
  for (int cb = s0; cb < s1; cb += ASM_CHUNK){
    const int cnt = (s1 - cb < ASM_CHUNK) ? (s1 - cb) : ASM_CHUNK;
    __syncthreads();
    for (int i = t; i < cnt; i += 192) ics[i] = cs_ta[cb + i];
    __syncthreads();
    int e = 0;
    for (; e + 8 <= cnt; e += 8){
      if (act){
        uint32_t b[8];
        #pragma unroll
        for (int j = 0; j < 8; ++j) b[j] = zT[(size_t)ics[e + j] * 192 + t];
        #pragma unroll
        for (int j = 0; j < 8; ++j) accT += fp8_dec1(b[j]);
      }
    }
    for (; e < cnt; ++e)
      if (act) accT += fp8_dec1((uint32_t)zT[(size_t)ics[e] * 192 + t]);
  }
  s0 = rs_aa[node]; s1 = rs_aa[node + 1];
  const float invA = 1.f / fmaxf((float)(s1 - s0), 1.f);
  for (int cb = s0; cb < s1; cb += ASM_CHUNK){
    const int cnt = (s1 - cb < ASM_CHUNK) ? (s1 - cb) : ASM_CHUNK;
    __syncthreads();
    for (int i = t; i < cnt; i += 192) ics[i] = cs_aa[cb + i];
    __syncthreads();
    int e = 0;
    for (; e + 8 <= cnt; e += 8){
      if (act){
        uint32_t b[8];
        #pragma unroll
        for (int j = 0; j < 8; ++j) b[j] = zA[(size_t)ics[e + j] * 192 + t];
        #pragma unroll
        for (int j = 0; j < 8; ++j) accA += fp8_dec1(b[j]);
      }
    }
    for (; e < cnt; ++e)
      if (act) accA += fp8_dec1((uint32_t)zA[(size_t)ics[e] * 192 + t]);
  }
  float* orow = ((h == 0) ? o0 : ((h == 1) ? o1 : o2)) + (size_t)node * Oh + (t - base);
  float v = 0.f;
  if (act) v = *orow + accT * invT + accA * invA;
  __syncthreads();
  if (act) sb[t] = v;
  __syncthreads();
  const int wv = t >> 6, ln = t & 63;
  {
    const int b = (wv == 0) ? 0 : ((wv == 1) ? 129 : 161);
    const int W = (wv == 0) ? 129 : ((wv == 1) ? 32 : 18);
    float m = -3.4e38f;
    for (int i = ln; i < W; i += 64) m = fmaxf(m, sb[b + i]);
    #pragma unroll
    for (int o = 32; o; o >>= 1) m = fmaxf(m, __shfl_xor(m, o));
    float s = 0.f;
    for (int i = ln; i < W; i += 64) s += expf(sb[b + i] - m);
    #pragma unroll
    for (int o = 32; o; o >>= 1) s += __shfl_xor(s, o);
    if (ln == 0) lse[wv] = m + logf(s);
  }
  __syncthreads();
  if (act) *orow = v - lse[h];
}

// ---------------- host ----------------
extern "C" void kernel_launch(void* const* d_in, const int* in_sizes, int n_in,
                              void* d_out, int out_size, void* d_ws, size_t ws_size,
                              hipStream_t stream){
  (void)n_in; (void)out_size; (void)ws_size;
  const float* xa  = (const float*)d_in[0];
  const float* xt  = (const float*)d_in[1];
  const int*   e_at = (const int*)d_in[2];
  const int*   e_ta = (const int*)d_in[3];
  const int*   e_aa = (const int*)d_in[4];
  const float* Wl1 = (const float*)d_in[5];
  const float* Wr1 = (const float*)d_in[6];
  const float* b1  = (const float*)d_in[7];
  const float* Wl2_[3] = {(const float*)d_in[8],  (const float*)d_in[11], (const float*)d_in[14]};
  const float* Wr2_[3] = {(const float*)d_in[9],  (const float*)d_in[12], (const float*)d_in[15]};
  const float* b2_[3]  = {(const float*)d_in[10], (const float*)d_in[13], (const float*)d_in[16]};

  const int NA = in_sizes[0] / 128;
  const int NT = in_sizes[1] / 128;
  const int EAT = in_sizes[2] / 2, ETA = in_sizes[3] / 2, EAA = in_sizes[4] / 2;
  const int Ov[3] = {129, 32, 18};
  const int og[3] = {0, 129, 161};

  // -------- workspace layout (~268 MB) --------
  char* Wp = (char*)d_ws;
  size_t off = 0;
  auto alloc = [&](size_t bytes)->char*{
    char* p = Wp + off; off = (off + bytes + 255) & ~(size_t)255; return p;
  };
  // slot0: first holds xa_8|xt_8 (fp8, for aggs); later overwritten by xa_b (bf16, GEMM A)
  char* slot0 = alloc((size_t)NA * 128 * 2);
  uint8_t* xa_8 = (uint8_t*)slot0;
  uint8_t* xt_8 = (uint8_t*)(slot0 + (size_t)NA * 128);
  bf16* xa_b = (bf16*)slot0;
  bf16* xt_b = (bf16*)alloc((size_t)NT * 128 * 2);
  bf16* m_at = (bf16*)alloc((size_t)NT * 128 * 2);
  bf16* m_ta = (bf16*)alloc((size_t)NA * 128 * 2);
  bf16* m_aa = (bf16*)alloc((size_t)NA * 128 * 2);
  bf16* h_a  = (bf16*)alloc((size_t)NA * 256 * 2);
  bf16* h_t  = (bf16*)alloc((size_t)NT * 256 * 2);
  uint8_t* zA_at = (uint8_t*)alloc((size_t)NA * 192);
  uint8_t* zT_ta = (uint8_t*)alloc((size_t)NT * 192);
  uint8_t* zA_aa = (uint8_t*)alloc((size_t)NA * 192);
  bf16* Bt_ha[3]; bf16* Bt_ht[3]; bf16* BT2a[3]; bf16* BT2t[3];
  float* bc1[3]; float* bc2[3];
  for (int g = 0; g < 3; ++g){
    Bt_ha[g] = (bf16*)alloc((size_t)256 * 384 * 2);
    Bt_ht[g] = (bf16*)alloc((size_t)256 * 256 * 2);
    BT2a[g]  = (bf16*)alloc((size_t)3 * 129 * 256 * 2);
    BT2t[g]  = (bf16*)alloc((size_t)2 * 129 * 256 * 2);
    bc1[g]   = (float*)alloc(256 * 4);
    bc2[g]   = (float*)alloc(129 * 4);
  }
  int* rs_at  = (int*)alloc((size_t)(NT + 1) * 4);
  int* rs_ta  = (int*)alloc((size_t)(NA + 1) * 4);
  int* rs_aa  = (int*)alloc((size_t)(NA + 1) * 4);
  int* cur_at = (int*)alloc((size_t)NT * 4);
  int* cur_ta = (int*)alloc((size_t)NA * 4);
  int* cur_aa = (int*)alloc((size_t)NA * 4);
  int* bsum   = (int*)alloc(2048 * 4);
  int* cs_at  = (int*)alloc((size_t)EAT * 4);
  int* cs_ta  = (int*)alloc((size_t)ETA * 4);
  int* cs_aa  = (int*)alloc((size_t)EAA * 4);

  // fp8 copies of x (for gathers)
  k_f2fp8<<<(NA * 128 / 4 + 255) / 256, 256, 0, stream>>>(xa, xa_8, NA * 128 / 4);
  k_f2fp8<<<(NT * 128 / 4 + 255) / 256, 256, 0, stream>>>(xt, xt_8, NT * 128 / 4);

  // weight prep for all 3 g's (1 launch each)
  for (int g = 0; g < 3; ++g){
    const int O = Ov[g];
    int tot = 256 * 384 + 256 * 256 + 3 * O * 256 + 2 * O * 256 + 256 + O;
    k_prep<<<(tot + 255) / 256, 256, 0, stream>>>(
        Wl1 + (size_t)(3 * g) * 128 * 256, Wr1 + (size_t)(3 * g) * 128 * 256,
        b1 + (size_t)(3 * g) * 256, Wl2_[g], Wr2_[g], b2_[g], O,
        Bt_ha[g], Bt_ht[g], BT2a[g], BT2t[g], bc1[g], bc2[g]);
  }

  // CSR build (shared by all 3 GNNs)
  auto build_csr = [&](const int* edges, int E, int n, int* rs, int* cur, int* cs){
    int ebl = (E + 255) / 256, nbl = (n + 255) / 256;
    k_zeroi<<<nbl, 256, 0, stream>>>(cur, n);
    k_deg<<<ebl, 256, 0, stream>>>(edges + E, cur, E);
    k_scan_partial<<<nbl, 256, 0, stream>>>(cur, rs, bsum, n);
    k_scan_bsum<<<1, 1024, 0, stream>>>(bsum, nbl, rs + n);
    k_scan_add<<<nbl, 256, 0, stream>>>(rs, bsum, n);
    k_zeroi<<<nbl, 256, 0, stream>>>(cur, n);
    k_fill<<<ebl, 256, 0, stream>>>(edges, edges + E, rs, cur, cs, E);
  };
  build_csr(e_at, EAT, NT, rs_at, cur_at, cs_at);
  build_csr(e_ta, ETA, NA, rs_ta, cur_ta, cs_ta);
  build_csr(e_aa, EAA, NA, rs_aa, cur_aa, cs_aa);

  // layer-1 mean aggregations from fp8 x (g-invariant), 4 nodes/block
  k_agg128_8<<<(NT + 3) / 4, 256, 0, stream>>>(xa_8, rs_at, cs_at, m_at, NT);
  k_agg128_8<<<(NA + 3) / 4, 256, 0, stream>>>(xt_8, rs_ta, cs_ta, m_ta, NA);
  k_agg128_8<<<(NA + 3) / 4, 256, 0, stream>>>(xa_8, rs_aa, cs_aa, m_aa, NA);

  // now overwrite slot0 with bf16 xa (GEMM A); xt_b separate
  k_f2bf<<<(NA * 128 / 4 + 255) / 256, 256, 0, stream>>>(xa, xa_b, NA * 128 / 4);
  k_f2bf<<<(NT * 128 / 4 + 255) / 256, 256, 0, stream>>>(xt, xt_b, NT * 128 / 4);

  // d_out head base offsets
  size_t offA[3], offT[3], cum = 0;
  for (int g = 0; g < 3; ++g){
    offA[g] = cum; offT[g] = cum + (size_t)NA * Ov[g];
    cum += (size_t)(NA + NT) * Ov[g];
  }

  for (int g = 0; g < 3; ++g){
    const int O = Ov[g];
    float* outA = (float*)d_out + offA[g];
    float* outT = (float*)d_out + offT[g];
    const float* b1g = b1 + (size_t)(3 * g) * 256;

    // dropout keys (threefry scheme verified R2-R10)
    uint32_t kg0, kg1, ka0, ka1, kt0, kt1;
    tf2x32(0u, 42u, 0u, (uint32_t)g, &kg0, &kg1);
    tf2x32(kg0, kg1, 0u, 0u, &ka0, &ka1);
    tf2x32(kg0, kg1, 0u, 1u, &kt0, &kt1);

    // layer 1 (MFMA + fused bias+relu+dropout), 128x256 tiles: single pass over A
    k_gemm_mfma<0><<<dim3(1, (NA + 127) / 128), 256, 0, stream>>>(
        m_ta, m_aa, xa_b, 128, Bt_ha[g], 384, NA, 256, 384,
        h_a, nullptr, nullptr, nullptr, bc1[g], 0, 0, ka0, ka1);
    k_gemm_mfma<0><<<dim3(1, (NT + 127) / 128), 256, 0, stream>>>(
        m_at, xt_b, xt_b, 128, Bt_ht[g], 256, NT, 256, 256,
        h_t, nullptr, nullptr, nullptr, b1g, 0, 0, kt0, kt1);

    // layer 2: one multi-strip GEMM per source, 128x256 tiles
    k_gemm_mfma<1><<<dim3((3 * O + 255) / 256, (NA + 127) / 128), 256, 0, stream>>>(
        h_a, h_a + 128, h_a, 256, BT2a[g], 256, NA, 3 * O, 256,
        nullptr, zA_at, zA_aa, outA, bc2[g], O, og[g], 0, 0);
    k_gemm_mfma<2><<<dim3((2 * O + 255) / 256, (NT + 127) / 128), 256, 0, stream>>>(
        h_t, h_t + 128, h_t, 256, BT2t[g], 256, NT, 2 * O, 256,
        nullptr, zT_ta, nullptr, outT, b2_[g], O, og[g], 0, 0);
  }

  // fused fp8 gather-mean + log_softmax over all 3 heads
  k_assemble_t<<<NT, 192, 0, stream>>>(zA_at, rs_at, cs_at,
                                       (float*)d_out + offT[0], (float*)d_out + offT[1],
                                       (float*)d_out + offT[2]);
  k_assemble_a<<<NA, 192, 0, stream>>>(zT_ta, zA_aa, rs_ta, cs_ta, rs_aa, cs_aa,
                                       (float*)d_out + offA[0], (float*)d_out + offA[1],
                                       (float*)d_out + offA[2]);
}

// Round 12
// 2073.736 us; speedup vs baseline: 2.1147x; 2.1147x over previous
//
#include <hip/hip_runtime.h>
#include <stdint.h>
#include <stddef.h>

typedef unsigned short bf16;
typedef __attribute__((ext_vector_type(8))) short short8;   // 8 bf16 (MFMA A/B frag)
typedef __attribute__((ext_vector_type(4))) float f32x4;    // MFMA C/D frag

__device__ __forceinline__ float bf2f(unsigned short u){
  union { uint32_t i; float f; } x; x.i = ((uint32_t)u) << 16; return x.f;
}
__device__ __forceinline__ unsigned short f2bf(float f){
  union { float f; uint32_t i; } x; x.f = f;
  uint32_t r = x.i + 0x7FFFu + ((x.i >> 16) & 1u);  // RNE
  return (unsigned short)(r >> 16);
}
__device__ __forceinline__ uint32_t pk2(float a, float b){
  return (uint32_t)f2bf(a) | ((uint32_t)f2bf(b) << 16);
}

// ---- fp8 e4m3fn (OCP) encode/decode -- internal compression only ----
__device__ __forceinline__ uint8_t f2fp8_sw(float f){
  uint32_t b = __float_as_uint(f);
  uint32_t s = (b >> 24) & 0x80u;
  uint32_t x = b & 0x7fffffffu;
  if (x >= 0x43e00000u) return (uint8_t)(s | 0x7eu);        // clamp to ±448
  if (x < 0x3c800000u){                                     // subnormal
    uint32_t q = (uint32_t)rintf(__uint_as_float(x) * 512.f);
    return (uint8_t)(s | q);
  }
  uint32_t lsb = (x >> 20) & 1u;
  x += 0x7ffffu + lsb;                                      // RNE at bit 20
  uint32_t u = (((x >> 23) - 120u) << 3) | ((x >> 20) & 7u);
  if (u > 0x7eu) u = 0x7eu;
  return (uint8_t)(s | u);
}
__device__ __forceinline__ float fp8_dec1_sw(uint32_t u){
  uint32_t e = (u >> 3) & 15u, m = u & 7u;
  float v = e ? __uint_as_float(((e + 120u) << 23) | (m << 20))
              : (float)m * 0.001953125f;
  return (u & 0x80u) ? -v : v;
}

#if __has_builtin(__builtin_amdgcn_cvt_pk_f32_fp8) && __has_builtin(__builtin_amdgcn_cvt_pk_fp8_f32)
#define FP8_HW 1
#else
#define FP8_HW 0
#endif

// single-byte decode: 1 VALU op (no LDS LUT -> no bank conflicts)
__device__ __forceinline__ float fp8_dec1(uint32_t b){
#if FP8_HW
  auto lo = __builtin_amdgcn_cvt_pk_f32_fp8((int)b, false);
  return lo[0];
#else
  return fp8_dec1_sw(b);
#endif
}
__device__ __forceinline__ void fp8_dec4(uint32_t w, float* o){
#if FP8_HW
  auto lo = __builtin_amdgcn_cvt_pk_f32_fp8((int)w, false);
  auto hi = __builtin_amdgcn_cvt_pk_f32_fp8((int)w, true);
  o[0] = lo[0]; o[1] = lo[1]; o[2] = hi[0]; o[3] = hi[1];
#else
  o[0] = fp8_dec1_sw(w & 0xffu);        o[1] = fp8_dec1_sw((w >> 8) & 0xffu);
  o[2] = fp8_dec1_sw((w >> 16) & 0xffu); o[3] = fp8_dec1_sw(w >> 24);
#endif
}
__device__ __forceinline__ uint8_t fp8_enc1(float v){
#if FP8_HW
  return (uint8_t)(__builtin_amdgcn_cvt_pk_fp8_f32(v, v, 0, false) & 0xff);
#else
  return f2fp8_sw(v);
#endif
}
__device__ __forceinline__ uint32_t fp8_enc4(float a, float b, float c, float d){
#if FP8_HW
  int w = 0;
  w = __builtin_amdgcn_cvt_pk_fp8_f32(a, b, w, false);
  w = __builtin_amdgcn_cvt_pk_fp8_f32(c, d, w, true);
  return (uint32_t)w;
#else
  return (uint32_t)f2fp8_sw(a) | ((uint32_t)f2fp8_sw(b) << 8)
       | ((uint32_t)f2fp8_sw(c) << 16) | ((uint32_t)f2fp8_sw(d) << 24);
#endif
}

// ---------------- threefry2x32 (matches harness jax; verified R2-R11) ----------------
__host__ __device__ __forceinline__ uint32_t rotl32_(uint32_t x, int d){
  return (x << d) | (x >> (32 - d));
}
__host__ __device__ inline void tf2x32(uint32_t k0, uint32_t k1, uint32_t x0, uint32_t x1,
                                       uint32_t* o0, uint32_t* o1){
  uint32_t k2 = k0 ^ k1 ^ 0x1BD11BDAu;
#define TF_R4(ra,rb,rc,rd) \
  x0 += x1; x1 = rotl32_(x1,ra); x1 ^= x0; \
  x0 += x1; x1 = rotl32_(x1,rb); x1 ^= x0; \
  x0 += x1; x1 = rotl32_(x1,rc); x1 ^= x0; \
  x0 += x1; x1 = rotl32_(x1,rd); x1 ^= x0;
  x0 += k0; x1 += k1;
  TF_R4(13,15,26,6)  x0 += k1; x1 += k2 + 1u;
  TF_R4(17,29,16,24) x0 += k2; x1 += k0 + 2u;
  TF_R4(13,15,26,6)  x0 += k0; x1 += k1 + 3u;
  TF_R4(17,29,16,24) x0 += k1; x1 += k2 + 4u;
  TF_R4(13,15,26,6)  x0 += k2; x1 += k0 + 5u;
  *o0 = x0; *o1 = x1;
#undef TF_R4
}

// ---------------- small utils ----------------
__global__ void k_zeroi(int* __restrict__ p, int n){
  int i = blockIdx.x * 256 + threadIdx.x;
  if (i < n) p[i] = 0;
}
__global__ void k_f2bf(const float* __restrict__ in, bf16* __restrict__ out, int n4){
  int i = blockIdx.x * 256 + threadIdx.x;
  if (i < n4){
    float4 v = ((const float4*)in)[i];
    ushort4 u; u.x = f2bf(v.x); u.y = f2bf(v.y); u.z = f2bf(v.z); u.w = f2bf(v.w);
    ((ushort4*)out)[i] = u;
  }
}
__global__ void k_f2fp8(const float* __restrict__ in, uint8_t* __restrict__ out, int n4){
  int i = blockIdx.x * 256 + threadIdx.x;
  if (i < n4){
    float4 v = ((const float4*)in)[i];
    ((uint32_t*)out)[i] = fp8_enc4(v.x, v.y, v.z, v.w);
  }
}

// ---------------- CSR build ----------------
__global__ void k_deg(const int* __restrict__ dst, int* __restrict__ deg, int E){
  int i = blockIdx.x * 256 + threadIdx.x;
  if (i < E) atomicAdd(&deg[dst[i]], 1);
}
__global__ __launch_bounds__(256)
void k_scan_partial(const int* __restrict__ in, int* __restrict__ exc,
                    int* __restrict__ bsum, int n){
  __shared__ int tmp[256];
  int t = threadIdx.x, i = blockIdx.x * 256 + t;
  int v = (i < n) ? in[i] : 0;
  tmp[t] = v; __syncthreads();
  #pragma unroll
  for (int off = 1; off < 256; off <<= 1){
    int u = (t >= off) ? tmp[t - off] : 0; __syncthreads();
    tmp[t] += u; __syncthreads();
  }
  if (i < n) exc[i] = tmp[t] - v;
  if (t == 255) bsum[blockIdx.x] = tmp[255];
}
__global__ __launch_bounds__(1024)
void k_scan_bsum(int* __restrict__ bsum, int nb, int* __restrict__ total_out){
  __shared__ int tmp[1024];
  int t = threadIdx.x;
  int v = (t < nb) ? bsum[t] : 0;
  tmp[t] = v; __syncthreads();
  #pragma unroll
  for (int off = 1; off < 1024; off <<= 1){
    int u = (t >= off) ? tmp[t - off] : 0; __syncthreads();
    tmp[t] += u; __syncthreads();
  }
  if (t < nb) bsum[t] = tmp[t] - v;
  if (t == 1023) *total_out = tmp[1023];
}
__global__ void k_scan_add(int* __restrict__ exc, const int* __restrict__ bsum, int n){
  int i = blockIdx.x * 256 + threadIdx.x;
  if (i < n) exc[i] += bsum[blockIdx.x];
}
__global__ void k_fill(const int* __restrict__ src, const int* __restrict__ dst,
                       const int* __restrict__ rs, int* __restrict__ cur,
                       int* __restrict__ cs, int E){
  int i = blockIdx.x * 256 + threadIdx.x;
  if (i < E){
    int d = dst[i];
    int p = atomicAdd(&cur[d], 1);
    cs[rs[d] + p] = src[i];
  }
}

// ---------------- layer-1 mean aggregation from fp8 x (128B rows) ----------------
// 4 nodes per 256-thread block (1 wave/node); per-wave LDS cs segment.
#define AGG_CHUNK 128
__global__ __launch_bounds__(256)
void k_agg128_8(const uint8_t* __restrict__ X8, const int* __restrict__ rs,
                const int* __restrict__ cs, bf16* __restrict__ out, int nNodes){
  __shared__ int ics4[4][AGG_CHUNK];
  const int wv = threadIdx.x >> 6, lane = threadIdx.x & 63;
  const int node = blockIdx.x * 4 + wv;
  if (node >= nNodes) return;
  int* ics = ics4[wv];
  const int hl = lane >> 5, cl = lane & 31;
  const int s0 = rs[node], s1 = rs[node + 1];
  float a[4] = {0.f, 0.f, 0.f, 0.f};
  for (int cb = s0; cb < s1; cb += AGG_CHUNK){
    const int cnt = (s1 - cb < AGG_CHUNK) ? (s1 - cb) : AGG_CHUNK;
    __builtin_amdgcn_wave_barrier();
    for (int i = lane; i < cnt; i += 64) ics[i] = cs[cb + i];
    __builtin_amdgcn_wave_barrier();
    int e = 0;
    for (; e + 16 <= cnt; e += 16){
      uint32_t w[8];
      #pragma unroll
      for (int j = 0; j < 8; ++j){
        int idx = ics[e + j * 2 + hl];
        w[j] = *(const uint32_t*)(X8 + (size_t)idx * 128 + (cl << 2));
      }
      #pragma unroll
      for (int j = 0; j < 8; ++j){
        float d[4];
        fp8_dec4(w[j], d);
        a[0] += d[0]; a[1] += d[1]; a[2] += d[2]; a[3] += d[3];
      }
    }
    for (; e + 2 <= cnt; e += 2){
      int idx = ics[e + hl];
      uint32_t w = *(const uint32_t*)(X8 + (size_t)idx * 128 + (cl << 2));
      float d[4];
      fp8_dec4(w, d);
      a[0] += d[0]; a[1] += d[1]; a[2] += d[2]; a[3] += d[3];
    }
    if (e < cnt && hl == 0){   // single leftover edge: low half only
      int idx = ics[e];
      uint32_t w = *(const uint32_t*)(X8 + (size_t)idx * 128 + (cl << 2));
      float d[4];
      fp8_dec4(w, d);
      a[0] += d[0]; a[1] += d[1]; a[2] += d[2]; a[3] += d[3];
    }
  }
  #pragma unroll
  for (int j = 0; j < 4; ++j) a[j] += __shfl_xor(a[j], 32);
  if (lane < 32){
    float inv = 1.f / fmaxf((float)(s1 - s0), 1.f);
    ushort4 u;
    u.x = f2bf(a[0] * inv); u.y = f2bf(a[1] * inv);
    u.z = f2bf(a[2] * inv); u.w = f2bf(a[3] * inv);
    *(ushort4*)(out + (size_t)node * 128 + (cl << 2)) = u;
  }
}

// ---------------- fused per-g weight prep ----------------
__global__ void k_prep(const float* __restrict__ Wl1g, const float* __restrict__ Wr1g,
                       const float* __restrict__ b1g,
                       const float* __restrict__ Wl2g, const float* __restrict__ Wr2g,
                       const float* __restrict__ b2g, int O,
                       bf16* __restrict__ Bt_ha, bf16* __restrict__ Bt_ht,
                       bf16* __restrict__ BT2a, bf16* __restrict__ BT2t,
                       float* __restrict__ bc1, float* __restrict__ bc2){
  int i = blockIdx.x * 256 + threadIdx.x;
  const int R0 = 256 * 384, R1 = 256 * 256;
  const int R2 = 3 * O * 256, R3 = 2 * O * 256;
  if (i < R0){
    int n = i / 384, k = i - n * 384;
    int seg = k >> 7, kk = k & 127;
    float v;
    if (seg == 0)      v = Wl1g[(size_t)(128 + kk) * 256 + n];
    else if (seg == 1) v = Wl1g[(size_t)(256 + kk) * 256 + n];
    else               v = Wr1g[(size_t)(128 + kk) * 256 + n] + Wr1g[(size_t)(256 + kk) * 256 + n];
    Bt_ha[(size_t)n * 384 + k] = f2bf(v);
    return;
  }
  i -= R0;
  if (i < R1){
    int n = i >> 8, k = i & 255;
    int kk = k & 127;
    float v = (k < 128) ? Wl1g[(size_t)kk * 256 + n] : Wr1g[(size_t)kk * 256 + n];
    Bt_ht[(size_t)n * 256 + k] = f2bf(v);
    return;
  }
  i -= R1;
  if (i < R2){
    int n = i >> 8, k = i & 255;
    int strip = n / O, r = n - strip * O;
    float v;
    if (strip == 0)      v = Wl2g[(size_t)k * O + r];
    else if (strip == 1) v = Wl2g[(size_t)512 * O + (size_t)k * O + r];
    else                 v = Wr2g[(size_t)256 * O + (size_t)k * O + r]
                           + Wr2g[(size_t)512 * O + (size_t)k * O + r];
    BT2a[(size_t)n * 256 + k] = f2bf(v);
    return;
  }
  i -= R2;
  if (i < R3){
    int n = i >> 8, k = i & 255;
    int strip = n / O, r = n - strip * O;
    float v = (strip == 0) ? Wl2g[(size_t)256 * O + (size_t)k * O + r]
                           : Wr2g[(size_t)k * O + r];
    BT2t[(size_t)n * 256 + k] = f2bf(v);
    return;
  }
  i -= R3;
  if (i < 256){ bc1[i] = b1g[256 + i] + b1g[512 + i]; return; }
  i -= 256;
  if (i < O) bc2[i] = b2g[O + i] + b2g[2 * O + i];
}

// ---------------- MFMA GEMM, 128x128 tile (4 waves, 4x4 frags/wave) — R10-proven ----------------
template<int EPI>
__global__ __launch_bounds__(256)
void k_gemm_mfma(const bf16* __restrict__ A0, const bf16* __restrict__ A1,
                 const bf16* __restrict__ A2, int lda,
                 const bf16* __restrict__ Bt, int ldb,
                 int M, int N, int Ktot,
                 bf16* __restrict__ hC,
                 uint8_t* __restrict__ z0, uint8_t* __restrict__ z1,
                 float* __restrict__ outF, const float* __restrict__ bias,
                 int O, int zoff, uint32_t dk0, uint32_t dk1){
  __shared__ bf16 As[128][40];   // 80B row stride: 16B-aligned, 2-way max bank alias
  __shared__ bf16 Bs[128][40];
  const int tid = threadIdx.x;
  const int w = tid >> 6, l = tid & 63;
  const int wr = w >> 1, wc = w & 1;
  const int r0 = blockIdx.y * 128, c0 = blockIdx.x * 128;

  f32x4 acc[4][4] = {};

  const int sm = tid >> 1, sk = (tid & 1) * 16;   // staging: row sm, 16 elems of 32
  const int arow = r0 + sm, brow = c0 + sm;
  const int lr = l & 15, g8 = (l >> 4) * 8;

  for (int kk = 0; kk < Ktot; kk += 32){
    const int seg = kk >> 7, koff = (kk & 127) + sk;
    const bf16* Ap = (seg == 0) ? A0 : ((seg == 1) ? A1 : A2);
    uint4 wa0 = {0,0,0,0}, wa1 = {0,0,0,0};
    if (arow < M){
      const uint4* p = (const uint4*)(Ap + (size_t)arow * lda + koff);
      wa0 = p[0]; wa1 = p[1];
    }
    uint4 wb0 = {0,0,0,0}, wb1 = {0,0,0,0};
    if (brow < N){
      const uint4* p = (const uint4*)(Bt + (size_t)brow * ldb + kk + sk);
      wb0 = p[0]; wb1 = p[1];
    }
    __syncthreads();
    *(uint4*)&As[sm][sk]     = wa0;
    *(uint4*)&As[sm][sk + 8] = wa1;
    *(uint4*)&Bs[sm][sk]     = wb0;
    *(uint4*)&Bs[sm][sk + 8] = wb1;
    __syncthreads();
    short8 af[4], bf[4];
    #pragma unroll
    for (int f = 0; f < 4; ++f){
      af[f] = *(const short8*)&As[wr * 64 + f * 16 + lr][g8];
      bf[f] = *(const short8*)&Bs[wc * 64 + f * 16 + lr][g8];
    }
    #pragma unroll
    for (int i = 0; i < 4; ++i)
      #pragma unroll
      for (int j = 0; j < 4; ++j)
        acc[i][j] = __builtin_amdgcn_mfma_f32_16x16x32_bf16(af[i], bf[j], acc[i][j], 0, 0, 0);
  }
  // C/D map: col=lane&15, row=(lane>>4)*4+reg
  #pragma unroll
  for (int rt = 0; rt < 4; ++rt){
    #pragma unroll
    for (int ct = 0; ct < 4; ++ct){
      #pragma unroll
      for (int r = 0; r < 4; ++r){
        int row = r0 + wr * 64 + rt * 16 + (l >> 4) * 4 + r;
        int col = c0 + wc * 64 + ct * 16 + lr;
        if (row < M && col < N){
          float v = acc[rt][ct][r];
          if (EPI == 0){
            v += bias[col];
            uint32_t o0, o1;
            tf2x32(dk0, dk1, 0u, (uint32_t)(row * 256 + col), &o0, &o1);
            float a = fmaxf(v, 0.f) * 2.f;
            hC[(size_t)row * 256 + col] = ((o0 ^ o1) >> 31) ? (bf16)0 : f2bf(a);
          } else {
            int s = (col >= O) + (EPI == 1 ? (col >= 2 * O) : 0);
            int lc = col - s * O;
            const int fs = (EPI == 1) ? 2 : 1;
            if (s == fs){
              outF[(size_t)row * O + lc] = v + bias[lc];
            } else {
              uint8_t* d = (s == 0) ? z0 : z1;
              d[(size_t)row * 192 + zoff + lc] = fp8_enc1(v);
            }
          }
        }
      }
    }
  }
}

// ---------------- fused assembles: LDS-staged cs + byte gather + VALU fp8 decode ----------
#define ASM_CHUNK 256
__global__ __launch_bounds__(192)
void k_assemble_t(const uint8_t* __restrict__ z, const int* __restrict__ rs,
                  const int* __restrict__ cs,
                  float* __restrict__ o0, float* __restrict__ o1, float* __restrict__ o2){
  __shared__ int ics[ASM_CHUNK];
  __shared__ float sb[179];
  __shared__ float lse[3];
  const int node = blockIdx.x, t = threadIdx.x;
  const bool act = t < 179;
  const int h = (t < 129) ? 0 : ((t < 161) ? 1 : 2);
  const int base = (h == 0) ? 0 : ((h == 1) ? 129 : 161);
  const int Oh = (h == 0) ? 129 : ((h == 1) ? 32 : 18);
  const int s0 = rs[node], s1 = rs[node + 1];
  float acc = 0.f;
  for (int cb = s0; cb < s1; cb += ASM_CHUNK){
    const int cnt = (s1 - cb < ASM_CHUNK) ? (s1 - cb) : ASM_CHUNK;
    __syncthreads();
    for (int i = t; i < cnt; i += 192) ics[i] = cs[cb + i];
    __syncthreads();
    int e = 0;
    for (; e + 8 <= cnt; e += 8){
      if (act){
        uint32_t b[8];
        #pragma unroll
        for (int j = 0; j < 8; ++j) b[j] = z[(size_t)ics[e + j] * 192 + t];
        #pragma unroll
        for (int j = 0; j < 8; ++j) acc += fp8_dec1(b[j]);
      }
    }
    for (; e < cnt; ++e)
      if (act) acc += fp8_dec1((uint32_t)z[(size_t)ics[e] * 192 + t]);
  }
  const float inv = 1.f / fmaxf((float)(s1 - s0), 1.f);
  float* orow = ((h == 0) ? o0 : ((h == 1) ? o1 : o2)) + (size_t)node * Oh + (t - base);
  float v = 0.f;
  if (act) v = *orow + acc * inv;
  __syncthreads();
  if (act) sb[t] = v;
  __syncthreads();
  const int wv = t >> 6, ln = t & 63;
  {
    const int b = (wv == 0) ? 0 : ((wv == 1) ? 129 : 161);
    const int W = (wv == 0) ? 129 : ((wv == 1) ? 32 : 18);
    float m = -3.4e38f;
    for (int i = ln; i < W; i += 64) m = fmaxf(m, sb[b + i]);
    #pragma unroll
    for (int o = 32; o; o >>= 1) m = fmaxf(m, __shfl_xor(m, o));
    float s = 0.f;
    for (int i = ln; i < W; i += 64) s += expf(sb[b + i] - m);
    #pragma unroll
    for (int o = 32; o; o >>= 1) s += __shfl_xor(s, o);
    if (ln == 0) lse[wv] = m + logf(s);
  }
  __syncthreads();
  if (act) *orow = v - lse[h];
}

__global__ __launch_bounds__(192)
void k_assemble_a(const uint8_t* __restrict__ zT, const uint8_t* __restrict__ zA,
                  const int* __restrict__ rs_ta, const int* __restrict__ cs_ta,
                  const int* __restrict__ rs_aa, const int* __restrict__ cs_aa,
                  float* __restrict__ o0, float* __restrict__ o1, float* __restrict__ o2){
  __shared__ int ics[ASM_CHUNK];
  __shared__ float sb[179];
  __shared__ float lse[3];
  const int node = blockIdx.x, t = threadIdx.x;
  const bool act = t < 179;
  const int h = (t < 129) ? 0 : ((t < 161) ? 1 : 2);
  const int base = (h == 0) ? 0 : ((h == 1) ? 129 : 161);
  const int Oh = (h == 0) ? 129 : ((h == 1) ? 32 : 18);
  float accT = 0.f, accA = 0.f;
  int s0 = rs_ta[node], s1 = rs_ta[node + 1];
  const float invT = 1.f / fmaxf((float)(s1 - s0), 1.f);
  for (int cb = s0; cb < s1; cb += ASM_CHUNK){
    const int cnt = (s1 - cb < ASM_CHUNK) ? (s1 - cb) : ASM_CHUNK;
    __syncthreads();
    for (int i = t; i < cnt; i += 192) ics[i] = cs_ta[cb + i];
    __syncthreads();
    int e = 0;
    for (; e + 8 <= cnt; e += 8){
      if (act){
        uint32_t b[8];
        #pragma unroll
        for (int j = 0; j < 8; ++j) b[j] = zT[(size_t)ics[e + j] * 192 + t];
        #pragma unroll
        for (int j = 0; j < 8; ++j) accT += fp8_dec1(b[j]);
      }
    }
    for (; e < cnt; ++e)
      if (act) accT += fp8_dec1((uint32_t)zT[(size_t)ics[e] * 192 + t]);
  }
  s0 = rs_aa[node]; s1 = rs_aa[node + 1];
  const float invA = 1.f / fmaxf((float)(s1 - s0), 1.f);
  for (int cb = s0; cb < s1; cb += ASM_CHUNK){
    const int cnt = (s1 - cb < ASM_CHUNK) ? (s1 - cb) : ASM_CHUNK;
    __syncthreads();
    for (int i = t; i < cnt; i += 192) ics[i] = cs_aa[cb + i];
    __syncthreads();
    int e = 0;
    for (; e + 8 <= cnt; e += 8){
      if (act){
        uint32_t b[8];
        #pragma unroll
        for (int j = 0; j < 8; ++j) b[j] = zA[(size_t)ics[e + j] * 192 + t];
        #pragma unroll
        for (int j = 0; j < 8; ++j) accA += fp8_dec1(b[j]);
      }
    }
    for (; e < cnt; ++e)
      if (act) accA += fp8_dec1((uint32_t)zA[(size_t)ics[e] * 192 + t]);
  }
  float* orow = ((h == 0) ? o0 : ((h == 1) ? o1 : o2)) + (size_t)node * Oh + (t - base);
  float v = 0.f;
  if (act) v = *orow + accT * invT + accA * invA;
  __syncthreads();
  if (act) sb[t] = v;
  __syncthreads();
  const int wv = t >> 6, ln = t & 63;
  {
    const int b = (wv == 0) ? 0 : ((wv == 1) ? 129 : 161);
    const int W = (wv == 0) ? 129 : ((wv == 1) ? 32 : 18);
    float m = -3.4e38f;
    for (int i = ln; i < W; i += 64) m = fmaxf(m, sb[b + i]);
    #pragma unroll
    for (int o = 32; o; o >>= 1) m = fmaxf(m, __shfl_xor(m, o));
    float s = 0.f;
    for (int i = ln; i < W; i += 64) s += expf(sb[b + i] - m);
    #pragma unroll
    for (int o = 32; o; o >>= 1) s += __shfl_xor(s, o);
    if (ln == 0) lse[wv] = m + logf(s);
  }
  __syncthreads();
  if (act) *orow = v - lse[h];
}

// ---------------- host ----------------
extern "C" void kernel_launch(void* const* d_in, const int* in_sizes, int n_in,
                              void* d_out, int out_size, void* d_ws, size_t ws_size,
                              hipStream_t stream){
  (void)n_in; (void)out_size; (void)ws_size;
  const float* xa  = (const float*)d_in[0];
  const float* xt  = (const float*)d_in[1];
  const int*   e_at = (const int*)d_in[2];
  const int*   e_ta = (const int*)d_in[3];
  const int*   e_aa = (const int*)d_in[4];
  const float* Wl1 = (const float*)d_in[5];
  const float* Wr1 = (const float*)d_in[6];
  const float* b1  = (const float*)d_in[7];
  const float* Wl2_[3] = {(const float*)d_in[8],  (const float*)d_in[11], (const float*)d_in[14]};
  const float* Wr2_[3] = {(const float*)d_in[9],  (const float*)d_in[12], (const float*)d_in[15]};
  const float* b2_[3]  = {(const float*)d_in[10], (const float*)d_in[13], (const float*)d_in[16]};

  const int NA = in_sizes[0] / 128;
  const int NT = in_sizes[1] / 128;
  const int EAT = in_sizes[2] / 2, ETA = in_sizes[3] / 2, EAA = in_sizes[4] / 2;
  const int Ov[3] = {129, 32, 18};
  const int og[3] = {0, 129, 161};

  // -------- workspace layout (~268 MB) --------
  char* Wp = (char*)d_ws;
  size_t off = 0;
  auto alloc = [&](size_t bytes)->char*{
    char* p = Wp + off; off = (off + bytes + 255) & ~(size_t)255; return p;
  };
  // slot0: first holds xa_8|xt_8 (fp8, for aggs); later overwritten by xa_b (bf16, GEMM A)
  char* slot0 = alloc((size_t)NA * 128 * 2);
  uint8_t* xa_8 = (uint8_t*)slot0;
  uint8_t* xt_8 = (uint8_t*)(slot0 + (size_t)NA * 128);
  bf16* xa_b = (bf16*)slot0;
  bf16* xt_b = (bf16*)alloc((size_t)NT * 128 * 2);
  bf16* m_at = (bf16*)alloc((size_t)NT * 128 * 2);
  bf16* m_ta = (bf16*)alloc((size_t)NA * 128 * 2);
  bf16* m_aa = (bf16*)alloc((size_t)NA * 128 * 2);
  bf16* h_a  = (bf16*)alloc((size_t)NA * 256 * 2);
  bf16* h_t  = (bf16*)alloc((size_t)NT * 256 * 2);
  uint8_t* zA_at = (uint8_t*)alloc((size_t)NA * 192);
  uint8_t* zT_ta = (uint8_t*)alloc((size_t)NT * 192);
  uint8_t* zA_aa = (uint8_t*)alloc((size_t)NA * 192);
  bf16* Bt_ha[3]; bf16* Bt_ht[3]; bf16* BT2a[3]; bf16* BT2t[3];
  float* bc1[3]; float* bc2[3];
  for (int g = 0; g < 3; ++g){
    Bt_ha[g] = (bf16*)alloc((size_t)256 * 384 * 2);
    Bt_ht[g] = (bf16*)alloc((size_t)256 * 256 * 2);
    BT2a[g]  = (bf16*)alloc((size_t)3 * 129 * 256 * 2);
    BT2t[g]  = (bf16*)alloc((size_t)2 * 129 * 256 * 2);
    bc1[g]   = (float*)alloc(256 * 4);
    bc2[g]   = (float*)alloc(129 * 4);
  }
  int* rs_at  = (int*)alloc((size_t)(NT + 1) * 4);
  int* rs_ta  = (int*)alloc((size_t)(NA + 1) * 4);
  int* rs_aa  = (int*)alloc((size_t)(NA + 1) * 4);
  int* cur_at = (int*)alloc((size_t)NT * 4);
  int* cur_ta = (int*)alloc((size_t)NA * 4);
  int* cur_aa = (int*)alloc((size_t)NA * 4);
  int* bsum   = (int*)alloc(2048 * 4);
  int* cs_at  = (int*)alloc((size_t)EAT * 4);
  int* cs_ta  = (int*)alloc((size_t)ETA * 4);
  int* cs_aa  = (int*)alloc((size_t)EAA * 4);

  // fp8 copies of x (for gathers)
  k_f2fp8<<<(NA * 128 / 4 + 255) / 256, 256, 0, stream>>>(xa, xa_8, NA * 128 / 4);
  k_f2fp8<<<(NT * 128 / 4 + 255) / 256, 256, 0, stream>>>(xt, xt_8, NT * 128 / 4);

  // weight prep for all 3 g's (1 launch each)
  for (int g = 0; g < 3; ++g){
    const int O = Ov[g];
    int tot = 256 * 384 + 256 * 256 + 3 * O * 256 + 2 * O * 256 + 256 + O;
    k_prep<<<(tot + 255) / 256, 256, 0, stream>>>(
        Wl1 + (size_t)(3 * g) * 128 * 256, Wr1 + (size_t)(3 * g) * 128 * 256,
        b1 + (size_t)(3 * g) * 256, Wl2_[g], Wr2_[g], b2_[g], O,
        Bt_ha[g], Bt_ht[g], BT2a[g], BT2t[g], bc1[g], bc2[g]);
  }

  // CSR build (shared by all 3 GNNs)
  auto build_csr = [&](const int* edges, int E, int n, int* rs, int* cur, int* cs){
    int ebl = (E + 255) / 256, nbl = (n + 255) / 256;
    k_zeroi<<<nbl, 256, 0, stream>>>(cur, n);
    k_deg<<<ebl, 256, 0, stream>>>(edges + E, cur, E);
    k_scan_partial<<<nbl, 256, 0, stream>>>(cur, rs, bsum, n);
    k_scan_bsum<<<1, 1024, 0, stream>>>(bsum, nbl, rs + n);
    k_scan_add<<<nbl, 256, 0, stream>>>(rs, bsum, n);
    k_zeroi<<<nbl, 256, 0, stream>>>(cur, n);
    k_fill<<<ebl, 256, 0, stream>>>(edges, edges + E, rs, cur, cs, E);
  };
  build_csr(e_at, EAT, NT, rs_at, cur_at, cs_at);
  build_csr(e_ta, ETA, NA, rs_ta, cur_ta, cs_ta);
  build_csr(e_aa, EAA, NA, rs_aa, cur_aa, cs_aa);

  // layer-1 mean aggregations from fp8 x (g-invariant), 4 nodes/block
  k_agg128_8<<<(NT + 3) / 4, 256, 0, stream>>>(xa_8, rs_at, cs_at, m_at, NT);
  k_agg128_8<<<(NA + 3) / 4, 256, 0, stream>>>(xt_8, rs_ta, cs_ta, m_ta, NA);
  k_agg128_8<<<(NA + 3) / 4, 256, 0, stream>>>(xa_8, rs_aa, cs_aa, m_aa, NA);

  // now overwrite slot0 with bf16 xa (GEMM A); xt_b separate
  k_f2bf<<<(NA * 128 / 4 + 255) / 256, 256, 0, stream>>>(xa, xa_b, NA * 128 / 4);
  k_f2bf<<<(NT * 128 / 4 + 255) / 256, 256, 0, stream>>>(xt, xt_b, NT * 128 / 4);

  // d_out head base offsets
  size_t offA[3], offT[3], cum = 0;
  for (int g = 0; g < 3; ++g){
    offA[g] = cum; offT[g] = cum + (size_t)NA * Ov[g];
    cum += (size_t)(NA + NT) * Ov[g];
  }

  for (int g = 0; g < 3; ++g){
    const int O = Ov[g];
    float* outA = (float*)d_out + offA[g];
    float* outT = (float*)d_out + offT[g];
    const float* b1g = b1 + (size_t)(3 * g) * 256;

    // dropout keys (threefry scheme verified R2-R11)
    uint32_t kg0, kg1, ka0, ka1, kt0, kt1;
    tf2x32(0u, 42u, 0u, (uint32_t)g, &kg0, &kg1);
    tf2x32(kg0, kg1, 0u, 0u, &ka0, &ka1);
    tf2x32(kg0, kg1, 0u, 1u, &kt0, &kt1);

    // layer 1 (MFMA + fused bias+relu+dropout), 128x128 tiles
    k_gemm_mfma<0><<<dim3(2, (NA + 127) / 128), 256, 0, stream>>>(
        m_ta, m_aa, xa_b, 128, Bt_ha[g], 384, NA, 256, 384,
        h_a, nullptr, nullptr, nullptr, bc1[g], 0, 0, ka0, ka1);
    k_gemm_mfma<0><<<dim3(2, (NT + 127) / 128), 256, 0, stream>>>(
        m_at, xt_b, xt_b, 128, Bt_ht[g], 256, NT, 256, 256,
        h_t, nullptr, nullptr, nullptr, b1g, 0, 0, kt0, kt1);

    // layer 2: one multi-strip GEMM per source, 128x128 tiles
    k_gemm_mfma<1><<<dim3((3 * O + 127) / 128, (NA + 127) / 128), 256, 0, stream>>>(
        h_a, h_a + 128, h_a, 256, BT2a[g], 256, NA, 3 * O, 256,
        nullptr, zA_at, zA_aa, outA, bc2[g], O, og[g], 0, 0);
    k_gemm_mfma<2><<<dim3((2 * O + 127) / 128, (NT + 127) / 128), 256, 0, stream>>>(
        h_t, h_t + 128, h_t, 256, BT2t[g], 256, NT, 2 * O, 256,
        nullptr, zT_ta, nullptr, outT, b2_[g], O, og[g], 0, 0);
  }

  // fused fp8 gather-mean + log_softmax over all 3 heads
  k_assemble_t<<<NT, 192, 0, stream>>>(zA_at, rs_at, cs_at,
                                       (float*)d_out + offT[0], (float*)d_out + offT[1],
                                       (float*)d_out + offT[2]);
  k_assemble_a<<<NA, 192, 0, stream>>>(zT_ta, zA_aa, rs_ta, cs_ta, rs_aa, cs_aa,
                                       (float*)d_out + offA[0], (float*)d_out + offA[1],
                                       (float*)d_out + offA[2]);
}